// Round 1
// baseline (375.854 us; speedup 1.0000x reference)
//
#include <hip/hip_runtime.h>

#define N_NODES 2048
#define N_EDGES 8192
#define EDGE_DIM 10
#define EDGE_HIDDEN 32
#define HID 160
#define GC (EDGE_HIDDEN * HID)   // 5120 columns of G

// ---------------- utility ----------------
__global__ void k_zero(float* p, int n) {
    int i = blockIdx.x * blockDim.x + threadIdx.x;
    if (i < n) p[i] = 0.f;
}

__global__ void k_count(const int* __restrict__ ei, float* __restrict__ cnt) {
    int e = blockIdx.x * blockDim.x + threadIdx.x;
    if (e < N_EDGES) atomicAdd(&cnt[ei[N_EDGES + e]], 1.f);
}

// h = relu(edge_attr @ w1 + b1)   [E, 32]
__global__ void k_h(const float* __restrict__ ea, const float* __restrict__ w1,
                    const float* __restrict__ b1, float* __restrict__ h) {
    int idx = blockIdx.x * blockDim.x + threadIdx.x;   // e*32 + j
    if (idx >= N_EDGES * EDGE_HIDDEN) return;
    int e = idx >> 5, j = idx & 31;
    float acc = b1[j];
#pragma unroll
    for (int i = 0; i < EDGE_DIM; ++i)
        acc += ea[e * EDGE_DIM + i] * w1[i * EDGE_HIDDEN + j];
    h[idx] = fmaxf(acc, 0.f);
}

// w2p[i][q*160+o] = w2[q][i*160+o]  -> standard GEMM layout [160, 5120]
__global__ void k_permute(const float* __restrict__ w2, float* __restrict__ w2p) {
    int idx = blockIdx.x * blockDim.x + threadIdx.x;
    if (idx >= HID * GC) return;
    int i = idx / GC;
    int r = idx - i * GC;
    int q = r / HID;
    int o = r - q * HID;
    w2p[idx] = w2[q * (HID * HID) + i * HID + o];
}

// per-node: rootx = x@root + bias ; xb = x @ b2(viewed [160,160])
__global__ void k_node(const float* __restrict__ x, const float* __restrict__ root,
                       const float* __restrict__ bias, const float* __restrict__ b2,
                       float* __restrict__ rootx, float* __restrict__ xb) {
    __shared__ float xs[HID];
    int n = blockIdx.x, o = threadIdx.x;   // blockDim = 160
    xs[o] = x[n * HID + o];
    __syncthreads();
    float ar = bias[o], ab = 0.f;
#pragma unroll 8
    for (int i = 0; i < HID; ++i) {
        float xi = xs[i];
        ar += xi * root[i * HID + o];
        ab += xi * b2[i * HID + o];
    }
    rootx[n * HID + o] = ar;
    xb[n * HID + o] = ab;
}

// G[2048,5120] = A[2048,160] @ B[160,5120]; 128x128 tile, 8x8 micro, fp32
#define TM 128
#define TN 128
#define TK 16
__global__ __launch_bounds__(256) void k_gemm(const float* __restrict__ A,
                                              const float* __restrict__ B,
                                              float* __restrict__ C) {
    __shared__ float As[TK][TM];
    __shared__ float Bs[TK][TN];
    int tid = threadIdx.x;
    int bn = blockIdx.x * TN;
    int bm = blockIdx.y * TM;
    int tx = tid & 15;       // n dir
    int ty = tid >> 4;       // m dir
    float acc[8][8];
#pragma unroll
    for (int i = 0; i < 8; ++i)
#pragma unroll
        for (int j = 0; j < 8; ++j) acc[i][j] = 0.f;

    for (int k0 = 0; k0 < HID; k0 += TK) {
        // stage A: 128x16 = 512 float4, 2 per thread
#pragma unroll
        for (int l = 0; l < 2; ++l) {
            int idx = tid + l * 256;
            int mloc = idx >> 2;
            int kloc = (idx & 3) * 4;
            float4 av = *(const float4*)&A[(size_t)(bm + mloc) * HID + k0 + kloc];
            As[kloc + 0][mloc] = av.x;
            As[kloc + 1][mloc] = av.y;
            As[kloc + 2][mloc] = av.z;
            As[kloc + 3][mloc] = av.w;
        }
        // stage B: 16x128 = 512 float4, 2 per thread
#pragma unroll
        for (int l = 0; l < 2; ++l) {
            int idx = tid + l * 256;
            int kloc = idx >> 5;
            int nloc = (idx & 31) * 4;
            *(float4*)&Bs[kloc][nloc] =
                *(const float4*)&B[(size_t)(k0 + kloc) * GC + bn + nloc];
        }
        __syncthreads();
#pragma unroll
        for (int kk = 0; kk < TK; ++kk) {
            float a[8], b[8];
            *(float4*)&a[0] = *(const float4*)&As[kk][ty * 8];
            *(float4*)&a[4] = *(const float4*)&As[kk][ty * 8 + 4];
            *(float4*)&b[0] = *(const float4*)&Bs[kk][tx * 8];
            *(float4*)&b[4] = *(const float4*)&Bs[kk][tx * 8 + 4];
#pragma unroll
            for (int i = 0; i < 8; ++i)
#pragma unroll
                for (int j = 0; j < 8; ++j) acc[i][j] += a[i] * b[j];
        }
        __syncthreads();
    }
#pragma unroll
    for (int i = 0; i < 8; ++i) {
        size_t row = (size_t)(bm + ty * 8 + i) * GC + bn + tx * 8;
        *(float4*)&C[row] = *(float4*)&acc[i][0];
        *(float4*)&C[row + 4] = *(float4*)&acc[i][4];
    }
}

// per edge: msg[o] = xb[src][o] + sum_q h[e][q]*G[src][q*160+o]; atomic into sum[dst]
__global__ void k_edge(const float* __restrict__ h, const float* __restrict__ G,
                       const float* __restrict__ xb, const int* __restrict__ ei,
                       float* __restrict__ sum) {
    __shared__ float hs[EDGE_HIDDEN];
    int e = blockIdx.x;
    int o = threadIdx.x;   // blockDim = 160
    int src = ei[e];
    int dst = ei[N_EDGES + e];
    if (o < EDGE_HIDDEN) hs[o] = h[e * EDGE_HIDDEN + o];
    __syncthreads();
    const float* Gr = &G[(size_t)src * GC];
    float m = xb[src * HID + o];
#pragma unroll 8
    for (int q = 0; q < EDGE_HIDDEN; ++q)
        m += hs[q] * Gr[q * HID + o];
    atomicAdd(&sum[dst * HID + o], m);
}

// out = sum/max(cnt,1) + rootx  (+relu)
__global__ void k_final(const float* __restrict__ sum, const float* __restrict__ cnt,
                        const float* __restrict__ rootx, float* __restrict__ out,
                        int relu) {
    int idx = blockIdx.x * blockDim.x + threadIdx.x;
    if (idx >= N_NODES * HID) return;
    int n = idx / HID;
    float v = sum[idx] / fmaxf(cnt[n], 1.f) + rootx[idx];
    out[idx] = relu ? fmaxf(v, 0.f) : v;
}

extern "C" void kernel_launch(void* const* d_in, const int* in_sizes, int n_in,
                              void* d_out, int out_size, void* d_ws, size_t ws_size,
                              hipStream_t stream) {
    const float* x     = (const float*)d_in[0];
    const float* ea    = (const float*)d_in[1];
    const float* w1a   = (const float*)d_in[2];
    const float* b1a   = (const float*)d_in[3];
    const float* w2a   = (const float*)d_in[4];
    const float* b2a   = (const float*)d_in[5];
    const float* roota = (const float*)d_in[6];
    const float* biasa = (const float*)d_in[7];
    const float* w1b   = (const float*)d_in[8];
    const float* b1b   = (const float*)d_in[9];
    const float* w2b   = (const float*)d_in[10];
    const float* b2b   = (const float*)d_in[11];
    const float* rootb = (const float*)d_in[12];
    const float* biasb = (const float*)d_in[13];
    const int*   ei    = (const int*)d_in[14];
    float* out = (float*)d_out;

    float* ws = (float*)d_ws;
    float* G     = ws; ws += (size_t)N_NODES * GC;          // 10,485,760
    float* h_a   = ws; ws += N_EDGES * EDGE_HIDDEN;         // 262,144
    float* h_b   = ws; ws += N_EDGES * EDGE_HIDDEN;
    float* w2pa  = ws; ws += HID * GC;                      // 819,200
    float* w2pb  = ws; ws += HID * GC;
    float* xb    = ws; ws += N_NODES * HID;                 // 327,680
    float* rootx = ws; ws += N_NODES * HID;
    float* sumb  = ws; ws += N_NODES * HID;
    float* cnt   = ws; ws += N_NODES;
    float* x1    = ws; ws += N_NODES * HID;
    float* x2    = ws; ws += N_NODES * HID;

    // shared pre-computation (h for conv2 is reused by layers 2 and 3)
    k_permute<<<(HID * GC + 255) / 256, 256, 0, stream>>>(w2a, w2pa);
    k_permute<<<(HID * GC + 255) / 256, 256, 0, stream>>>(w2b, w2pb);
    k_h<<<(N_EDGES * EDGE_HIDDEN + 255) / 256, 256, 0, stream>>>(ea, w1a, b1a, h_a);
    k_h<<<(N_EDGES * EDGE_HIDDEN + 255) / 256, 256, 0, stream>>>(ea, w1b, b1b, h_b);
    k_zero<<<(N_NODES + 255) / 256, 256, 0, stream>>>(cnt, N_NODES);
    k_count<<<(N_EDGES + 255) / 256, 256, 0, stream>>>(ei, cnt);

    struct Layer {
        const float *in, *h, *w2p, *b2, *root, *bias;
        float* out;
        int relu;
    };
    Layer L[3] = {
        {x,  h_a, w2pa, b2a, roota, biasa, x1, 1},
        {x1, h_b, w2pb, b2b, rootb, biasb, x2, 1},
        {x2, h_b, w2pb, b2b, rootb, biasb, out, 0},
    };

    for (int l = 0; l < 3; ++l) {
        k_node<<<N_NODES, HID, 0, stream>>>(L[l].in, L[l].root, L[l].bias, L[l].b2,
                                            rootx, xb);
        k_gemm<<<dim3(GC / TN, N_NODES / TM), 256, 0, stream>>>(L[l].in, L[l].w2p, G);
        k_zero<<<(N_NODES * HID + 255) / 256, 256, 0, stream>>>(sumb, N_NODES * HID);
        k_edge<<<N_EDGES, HID, 0, stream>>>(L[l].h, G, xb, ei, sumb);
        k_final<<<(N_NODES * HID + 255) / 256, 256, 0, stream>>>(sumb, cnt, rootx,
                                                                 L[l].out, L[l].relu);
    }
}

// Round 2
// 283.215 us; speedup vs baseline: 1.3271x; 1.3271x over previous
//
#include <hip/hip_runtime.h>

#define NN 2048
#define NE 8192
#define ED 10
#define EH 32
#define HID 160
#define NCOL 5504   // 32*160 (w2) + 160 (b2) + 160 (root) + 64 pad

typedef __attribute__((ext_vector_type(8))) short short8;
typedef __attribute__((ext_vector_type(4))) float f32x4;

__device__ __forceinline__ void split_bf16(float v, ushort& hi, ushort& lo) {
    unsigned u = __float_as_uint(v);
    hi = (ushort)(u >> 16);
    float hf = __uint_as_float(u & 0xffff0000u);
    lo = (ushort)(__float_as_uint(v - hf) >> 16);
}

// ---- x (fp32) -> bf16 hi/lo pair ----
__global__ void k_cvt(const float* __restrict__ x, ushort* __restrict__ xh,
                      ushort* __restrict__ xl) {
    int i = blockIdx.x * 256 + threadIdx.x;
    if (i >= NN * HID) return;
    ushort h, l; split_bf16(x[i], h, l);
    xh[i] = h; xl[i] = l;
}

// ---- h = relu(ea @ w1 + b1)  [E, 32] ----
__global__ void k_h(const float* __restrict__ ea, const float* __restrict__ w1,
                    const float* __restrict__ b1, float* __restrict__ h) {
    int idx = blockIdx.x * 256 + threadIdx.x;
    if (idx >= NE * EH) return;
    int e = idx >> 5, j = idx & 31;
    float acc = b1[j];
#pragma unroll
    for (int i = 0; i < ED; ++i) acc += ea[e * ED + i] * w1[i * EH + j];
    h[idx] = fmaxf(acc, 0.f);
}

// ---- B_t[n][k] bf16 hi/lo: n<5120 -> w2, <5280 -> b2, <5440 -> root, else 0 ----
__global__ void k_prepB(const float* __restrict__ w2, const float* __restrict__ b2,
                        const float* __restrict__ root, ushort* __restrict__ Bh,
                        ushort* __restrict__ Bl) {
    int idx = blockIdx.x * 256 + threadIdx.x;   // idx = k*NCOL + n (coalesced reads)
    if (idx >= NCOL * HID) return;
    int k = idx / NCOL;
    int n = idx - k * NCOL;
    float v;
    if (n < 5120) {
        int q = n / HID, o = n - q * HID;
        v = w2[q * (HID * HID) + k * HID + o];
    } else if (n < 5280) {
        v = b2[k * HID + (n - 5120)];
    } else if (n < 5440) {
        v = root[k * HID + (n - 5280)];
    } else {
        v = 0.f;
    }
    ushort h, l; split_bf16(v, h, l);
    Bh[(size_t)n * HID + k] = h;
    Bl[(size_t)n * HID + k] = l;
}

// ---- CSR build ----
__global__ void k_zi(int* p, int n) {
    int i = blockIdx.x * 256 + threadIdx.x;
    if (i < n) p[i] = 0;
}
__global__ void k_count(const int* __restrict__ ei, int* __restrict__ deg) {
    int e = blockIdx.x * 256 + threadIdx.x;
    if (e < NE) atomicAdd(&deg[ei[NE + e]], 1);
}
__global__ void k_scan(const int* __restrict__ deg, int* __restrict__ off,
                       int* __restrict__ cursor, float* __restrict__ dinv) {
    __shared__ int ps[256];
    int t = threadIdx.x;           // 256 threads x 8 bins
    int loc[8], s = 0;
#pragma unroll
    for (int i = 0; i < 8; ++i) { loc[i] = s; s += deg[t * 8 + i]; }
    ps[t] = s;
    __syncthreads();
    int total = s;
    for (int st = 1; st < 256; st <<= 1) {
        int v = (t >= st) ? ps[t - st] : 0;
        __syncthreads();
        ps[t] += v;
        __syncthreads();
    }
    int base = ps[t] - total;
#pragma unroll
    for (int i = 0; i < 8; ++i) {
        int b = t * 8 + i;
        off[b] = base + loc[i];
        cursor[b] = base + loc[i];
        dinv[b] = 1.0f / fmaxf((float)deg[b], 1.0f);
    }
}
__global__ void k_fill(const int* __restrict__ ei, int* __restrict__ cursor,
                       int* __restrict__ elist) {
    int e = blockIdx.x * 256 + threadIdx.x;
    if (e < NE) {
        int d = ei[NE + e];
        int p = atomicAdd(&cursor[d], 1);
        elist[p] = e;
    }
}

// ---- G[2048,5504] = x[2048,160] @ Bext[160,5504], bf16 split-3 MFMA ----
__global__ __launch_bounds__(256) void k_gemm(const ushort* __restrict__ Ah,
        const ushort* __restrict__ Al, const ushort* __restrict__ Bh,
        const ushort* __restrict__ Bl, float* __restrict__ G) {
    __shared__ ushort sAh[128 * 40], sAl[128 * 40], sBh[128 * 40], sBl[128 * 40];
    int tid = threadIdx.x;
    int bn = blockIdx.x * 128, bm = blockIdx.y * 128;
    int wid = tid >> 6, lane = tid & 63;
    int wm = (wid >> 1) * 64, wn = (wid & 1) * 64;
    int lr = lane & 15, lk = lane >> 4;     // row-in-tile, k-group
    f32x4 acc[4][4];
#pragma unroll
    for (int i = 0; i < 4; ++i)
#pragma unroll
        for (int j = 0; j < 4; ++j) acc[i][j] = (f32x4){0.f, 0.f, 0.f, 0.f};

    for (int c = 0; c < 5; ++c) {
        int k0 = c * 32;
#pragma unroll
        for (int i = 0; i < 2; ++i) {
            int s = tid + i * 256;
            int r = s >> 2, j = s & 3;      // row, 16B chunk (8 bf16)
            *(uint4*)&sAh[r * 40 + j * 8] = *(const uint4*)&Ah[(size_t)(bm + r) * HID + k0 + j * 8];
            *(uint4*)&sAl[r * 40 + j * 8] = *(const uint4*)&Al[(size_t)(bm + r) * HID + k0 + j * 8];
            *(uint4*)&sBh[r * 40 + j * 8] = *(const uint4*)&Bh[(size_t)(bn + r) * HID + k0 + j * 8];
            *(uint4*)&sBl[r * 40 + j * 8] = *(const uint4*)&Bl[(size_t)(bn + r) * HID + k0 + j * 8];
        }
        __syncthreads();
        short8 ah[4], al[4];
#pragma unroll
        for (int mt = 0; mt < 4; ++mt) {
            int r = wm + mt * 16 + lr;
            ah[mt] = *(const short8*)&sAh[r * 40 + lk * 8];
            al[mt] = *(const short8*)&sAl[r * 40 + lk * 8];
        }
#pragma unroll
        for (int nt = 0; nt < 4; ++nt) {
            int r = wn + nt * 16 + lr;
            short8 bh = *(const short8*)&sBh[r * 40 + lk * 8];
            short8 bl = *(const short8*)&sBl[r * 40 + lk * 8];
#pragma unroll
            for (int mt = 0; mt < 4; ++mt) {
                acc[mt][nt] = __builtin_amdgcn_mfma_f32_16x16x32_bf16(ah[mt], bh, acc[mt][nt], 0, 0, 0);
                acc[mt][nt] = __builtin_amdgcn_mfma_f32_16x16x32_bf16(ah[mt], bl, acc[mt][nt], 0, 0, 0);
                acc[mt][nt] = __builtin_amdgcn_mfma_f32_16x16x32_bf16(al[mt], bh, acc[mt][nt], 0, 0, 0);
            }
        }
        __syncthreads();
    }
#pragma unroll
    for (int mt = 0; mt < 4; ++mt)
#pragma unroll
        for (int nt = 0; nt < 4; ++nt) {
            int m0 = bm + wm + mt * 16 + lk * 4;
            int n = bn + wn + nt * 16 + lr;
#pragma unroll
            for (int r = 0; r < 4; ++r)
                G[(size_t)(m0 + r) * NCOL + n] = acc[mt][nt][r];
        }
}

// ---- per-dst aggregation + epilogue (mean, root, bias, relu, bf16 cvt) ----
__global__ void k_aggr(const float* __restrict__ G, const float* __restrict__ h,
                       const int* __restrict__ ei, const int* __restrict__ off,
                       const int* __restrict__ deg, const float* __restrict__ dinv,
                       const int* __restrict__ elist, const float* __restrict__ bias,
                       float* __restrict__ outf, ushort* __restrict__ oh,
                       ushort* __restrict__ ol, int relu_cvt) {
    int d = blockIdx.x, o = threadIdx.x;   // blockDim = 160
    float acc = 0.f;
    int o0 = off[d], dg = deg[d];
    for (int j = 0; j < dg; ++j) {
        int e = elist[o0 + j];
        int src = ei[e];
        const float* Gr = G + (size_t)src * NCOL;
        const float4* hp = (const float4*)(h + e * EH);
        float a = Gr[5120 + o];            // b2 (xb) term
#pragma unroll
        for (int qq = 0; qq < 8; ++qq) {
            float4 hv = hp[qq];
            a += hv.x * Gr[(qq * 4 + 0) * HID + o];
            a += hv.y * Gr[(qq * 4 + 1) * HID + o];
            a += hv.z * Gr[(qq * 4 + 2) * HID + o];
            a += hv.w * Gr[(qq * 4 + 3) * HID + o];
        }
        acc += a;
    }
    float v = acc * dinv[d] + G[(size_t)d * NCOL + 5280 + o] + bias[o];
    if (relu_cvt) {
        v = fmaxf(v, 0.f);
        ushort hi, lo; split_bf16(v, hi, lo);
        oh[d * HID + o] = hi;
        ol[d * HID + o] = lo;
    } else {
        outf[d * HID + o] = v;
    }
}

extern "C" void kernel_launch(void* const* d_in, const int* in_sizes, int n_in,
                              void* d_out, int out_size, void* d_ws, size_t ws_size,
                              hipStream_t stream) {
    const float* x     = (const float*)d_in[0];
    const float* ea    = (const float*)d_in[1];
    const float* w1a   = (const float*)d_in[2];
    const float* b1a   = (const float*)d_in[3];
    const float* w2a   = (const float*)d_in[4];
    const float* b2a   = (const float*)d_in[5];
    const float* roota = (const float*)d_in[6];
    const float* biasa = (const float*)d_in[7];
    const float* w1b   = (const float*)d_in[8];
    const float* b1b   = (const float*)d_in[9];
    const float* w2b   = (const float*)d_in[10];
    const float* b2b   = (const float*)d_in[11];
    const float* rootb = (const float*)d_in[12];
    const float* biasb = (const float*)d_in[13];
    const int*   ei    = (const int*)d_in[14];
    float* out = (float*)d_out;

    char* p = (char*)d_ws;
    float* G = (float*)p;          p += (size_t)NN * NCOL * 4;        // 45.1 MB
    ushort* BhA = (ushort*)p;      p += (size_t)NCOL * HID * 2;
    ushort* BlA = (ushort*)p;      p += (size_t)NCOL * HID * 2;
    ushort* BhB = (ushort*)p;      p += (size_t)NCOL * HID * 2;
    ushort* BlB = (ushort*)p;      p += (size_t)NCOL * HID * 2;
    float* h_a = (float*)p;        p += (size_t)NE * EH * 4;
    float* h_b = (float*)p;        p += (size_t)NE * EH * 4;
    ushort* xh = (ushort*)p;       p += (size_t)NN * HID * 2;
    ushort* xl = (ushort*)p;       p += (size_t)NN * HID * 2;
    int* deg = (int*)p;            p += NN * 4;
    int* off = (int*)p;            p += NN * 4;
    int* cursor = (int*)p;         p += NN * 4;
    float* dinv = (float*)p;       p += NN * 4;
    int* elist = (int*)p;          p += NE * 4;

    // one-time (per call) prep
    k_cvt<<<(NN * HID + 255) / 256, 256, 0, stream>>>(x, xh, xl);
    k_prepB<<<((size_t)NCOL * HID + 255) / 256, 256, 0, stream>>>(w2a, b2a, roota, BhA, BlA);
    k_prepB<<<((size_t)NCOL * HID + 255) / 256, 256, 0, stream>>>(w2b, b2b, rootb, BhB, BlB);
    k_h<<<(NE * EH + 255) / 256, 256, 0, stream>>>(ea, w1a, b1a, h_a);
    k_h<<<(NE * EH + 255) / 256, 256, 0, stream>>>(ea, w1b, b1b, h_b);
    k_zi<<<(NN + 255) / 256, 256, 0, stream>>>(deg, NN);
    k_count<<<(NE + 255) / 256, 256, 0, stream>>>(ei, deg);
    k_scan<<<1, 256, 0, stream>>>(deg, off, cursor, dinv);
    k_fill<<<(NE + 255) / 256, 256, 0, stream>>>(ei, cursor, elist);

    struct Layer { const ushort *bh, *bl; const float *h, *bias; int relu; };
    Layer L[3] = {
        {BhA, BlA, h_a, biasa, 1},
        {BhB, BlB, h_b, biasb, 1},
        {BhB, BlB, h_b, biasb, 0},
    };
    for (int l = 0; l < 3; ++l) {
        k_gemm<<<dim3(NCOL / 128, NN / 128), 256, 0, stream>>>(xh, xl, L[l].bh, L[l].bl, G);
        k_aggr<<<NN, HID, 0, stream>>>(G, L[l].h, ei, off, deg, dinv, elist,
                                       L[l].bias, out, xh, xl, L[l].relu);
    }
}

// Round 3
// 240.188 us; speedup vs baseline: 1.5648x; 1.1791x over previous
//
#include <hip/hip_runtime.h>

#define NN 2048
#define NE 8192
#define ED 10
#define EH 32
#define HID 160
#define NCOL 5504   // 32*160 (w2) + 160 (b2) + 160 (root) + 64 pad

typedef __attribute__((ext_vector_type(8))) short short8;
typedef __attribute__((ext_vector_type(4))) float f32x4;
typedef unsigned int u32;

__device__ __forceinline__ void split_bf16(float v, ushort& hi, ushort& lo) {
    unsigned u = __float_as_uint(v);
    hi = (ushort)(u >> 16);
    float hf = __uint_as_float(u & 0xffff0000u);
    lo = (ushort)(__float_as_uint(v - hf) >> 16);
}

// async global->LDS, 16B per lane; lds dest must be waveBase + lane*16
__device__ __forceinline__ void gl2lds16(const ushort* g, ushort* l) {
    __builtin_amdgcn_global_load_lds(
        (const __attribute__((address_space(1))) u32*)g,
        (__attribute__((address_space(3))) u32*)l, 16, 0, 0);
}

// ---- x (fp32) -> bf16 hi/lo pair ----
__global__ void k_cvt(const float* __restrict__ x, ushort* __restrict__ xh,
                      ushort* __restrict__ xl) {
    int i = blockIdx.x * 256 + threadIdx.x;
    if (i >= NN * HID) return;
    ushort h, l; split_bf16(x[i], h, l);
    xh[i] = h; xl[i] = l;
}

// ---- h = relu(ea @ w1 + b1)  [E, 32], both param sets in one launch ----
__global__ void k_h2(const float* __restrict__ ea,
                     const float* __restrict__ w1a, const float* __restrict__ b1a,
                     const float* __restrict__ w1b, const float* __restrict__ b1b,
                     float* __restrict__ ha, float* __restrict__ hb) {
    int idx = blockIdx.x * 256 + threadIdx.x;
    if (idx >= NE * EH) return;
    const float* w1 = blockIdx.y ? w1b : w1a;
    const float* b1 = blockIdx.y ? b1b : b1a;
    float* h = blockIdx.y ? hb : ha;
    int e = idx >> 5, j = idx & 31;
    float acc = b1[j];
#pragma unroll
    for (int i = 0; i < ED; ++i) acc += ea[e * ED + i] * w1[i * EH + j];
    h[idx] = fmaxf(acc, 0.f);
}

// ---- B_t[n][k] bf16 hi/lo, both param sets in one launch ----
__global__ void k_prepB2(const float* __restrict__ w2a, const float* __restrict__ b2a,
                         const float* __restrict__ roota,
                         const float* __restrict__ w2b, const float* __restrict__ b2b,
                         const float* __restrict__ rootb,
                         ushort* __restrict__ BhA, ushort* __restrict__ BlA,
                         ushort* __restrict__ BhB, ushort* __restrict__ BlB) {
    int idx = blockIdx.x * 256 + threadIdx.x;
    if (idx >= NCOL * HID) return;
    const float* w2 = blockIdx.y ? w2b : w2a;
    const float* b2 = blockIdx.y ? b2b : b2a;
    const float* root = blockIdx.y ? rootb : roota;
    ushort* Bh = blockIdx.y ? BhB : BhA;
    ushort* Bl = blockIdx.y ? BlB : BlA;
    int k = idx / NCOL;
    int n = idx - k * NCOL;
    float v;
    if (n < 5120) {
        int q = n / HID, o = n - q * HID;
        v = w2[q * (HID * HID) + k * HID + o];
    } else if (n < 5280) {
        v = b2[k * HID + (n - 5120)];
    } else if (n < 5440) {
        v = root[k * HID + (n - 5280)];
    } else {
        v = 0.f;
    }
    ushort h, l; split_bf16(v, h, l);
    Bh[(size_t)n * HID + k] = h;
    Bl[(size_t)n * HID + k] = l;
}

// ---- zero int region (covers sumb + degd + dego, laid out contiguously) ----
__global__ void k_zi(int* p, int n) {
    int i = blockIdx.x * 256 + threadIdx.x;
    if (i < n) p[i] = 0;
}
__global__ void k_count(const int* __restrict__ ei, int* __restrict__ degd,
                        int* __restrict__ dego) {
    int e = blockIdx.x * 256 + threadIdx.x;
    if (e < NE) {
        atomicAdd(&degd[ei[NE + e]], 1);
        atomicAdd(&dego[ei[e]], 1);
    }
}
// scan out-degrees -> src CSR offsets; dinv from dst degrees
__global__ void k_scan(const int* __restrict__ dego, const int* __restrict__ degd,
                       int* __restrict__ soff, int* __restrict__ cursor,
                       float* __restrict__ dinv) {
    __shared__ int ps[256];
    int t = threadIdx.x;           // 256 threads x 8 bins
    int loc[8], s = 0;
#pragma unroll
    for (int i = 0; i < 8; ++i) { loc[i] = s; s += dego[t * 8 + i]; }
    ps[t] = s;
    __syncthreads();
    int total = s;
    for (int st = 1; st < 256; st <<= 1) {
        int v = (t >= st) ? ps[t - st] : 0;
        __syncthreads();
        ps[t] += v;
        __syncthreads();
    }
    int base = ps[t] - total;
#pragma unroll
    for (int i = 0; i < 8; ++i) {
        int b = t * 8 + i;
        soff[b] = base + loc[i];
        cursor[b] = base + loc[i];
        dinv[b] = 1.0f / fmaxf((float)degd[b], 1.0f);
    }
}
__global__ void k_fill(const int* __restrict__ ei, int* __restrict__ cursor,
                       int* __restrict__ selist) {
    int e = blockIdx.x * 256 + threadIdx.x;
    if (e < NE) {
        int s = ei[e];
        int p = atomicAdd(&cursor[s], 1);
        selist[p] = e;
    }
}

// ---- G[2048,5504] = x[2048,160] @ Bext[160,5504], bf16 split-3 MFMA ----
// staging via global_load_lds width=16; unpadded 32-ushort k-rows (8/bank even)
__global__ __launch_bounds__(256) void k_gemm(const ushort* __restrict__ Ah,
        const ushort* __restrict__ Al, const ushort* __restrict__ Bh,
        const ushort* __restrict__ Bl, float* __restrict__ G) {
    __shared__ ushort sAh[128 * 32], sAl[128 * 32], sBh[128 * 32], sBl[128 * 32];
    int tid = threadIdx.x;
    int bn = blockIdx.x * 128, bm = blockIdx.y * 128;
    int wid = tid >> 6, lane = tid & 63;
    int wm = (wid >> 1) * 64, wn = (wid & 1) * 64;
    int lr = lane & 15, lk = lane >> 4;     // row-in-tile, k-group
    f32x4 acc[4][4];
#pragma unroll
    for (int i = 0; i < 4; ++i)
#pragma unroll
        for (int j = 0; j < 4; ++j) acc[i][j] = (f32x4){0.f, 0.f, 0.f, 0.f};

    for (int c = 0; c < 5; ++c) {
        int k0 = c * 32;
#pragma unroll
        for (int i = 0; i < 2; ++i) {
            int s = tid + i * 256;          // 16B chunk index 0..511
            int r = s >> 2, go = (s & 3) * 8;
            gl2lds16(&Ah[(size_t)(bm + r) * HID + k0 + go], &sAh[s * 8]);
            gl2lds16(&Al[(size_t)(bm + r) * HID + k0 + go], &sAl[s * 8]);
            gl2lds16(&Bh[(size_t)(bn + r) * HID + k0 + go], &sBh[s * 8]);
            gl2lds16(&Bl[(size_t)(bn + r) * HID + k0 + go], &sBl[s * 8]);
        }
        __syncthreads();
        short8 ah[4], al[4];
#pragma unroll
        for (int mt = 0; mt < 4; ++mt) {
            int r = wm + mt * 16 + lr;
            ah[mt] = *(const short8*)&sAh[r * 32 + lk * 8];
            al[mt] = *(const short8*)&sAl[r * 32 + lk * 8];
        }
#pragma unroll
        for (int nt = 0; nt < 4; ++nt) {
            int r = wn + nt * 16 + lr;
            short8 bh = *(const short8*)&sBh[r * 32 + lk * 8];
            short8 bl = *(const short8*)&sBl[r * 32 + lk * 8];
#pragma unroll
            for (int mt = 0; mt < 4; ++mt) {
                acc[mt][nt] = __builtin_amdgcn_mfma_f32_16x16x32_bf16(ah[mt], bh, acc[mt][nt], 0, 0, 0);
                acc[mt][nt] = __builtin_amdgcn_mfma_f32_16x16x32_bf16(ah[mt], bl, acc[mt][nt], 0, 0, 0);
                acc[mt][nt] = __builtin_amdgcn_mfma_f32_16x16x32_bf16(al[mt], bh, acc[mt][nt], 0, 0, 0);
            }
        }
        __syncthreads();
    }
#pragma unroll
    for (int mt = 0; mt < 4; ++mt)
#pragma unroll
        for (int nt = 0; nt < 4; ++nt) {
            int m0 = bm + wm + mt * 16 + lk * 4;
            int n = bn + wn + nt * 16 + lr;
#pragma unroll
            for (int r = 0; r < 4; ++r)
                G[(size_t)(m0 + r) * NCOL + n] = acc[mt][nt][r];
        }
}

// ---- src-grouped aggregation: G row in LDS, atomics into sumb[dst] ----
__global__ void k_aggr(const float* __restrict__ G, const float* __restrict__ h,
                       const int* __restrict__ ei, const int* __restrict__ soff,
                       const int* __restrict__ dego, const int* __restrict__ selist,
                       float* __restrict__ sumb) {
    __shared__ float Gs[5280];
    int s = blockIdx.x, t = threadIdx.x;   // blockDim = 160
    const float4* Grow = (const float4*)(G + (size_t)s * NCOL);
    for (int k = t; k < 1320; k += 160)
        ((float4*)Gs)[k] = Grow[k];
    __syncthreads();
    int o0 = soff[s], dg = dego[s];
    for (int j = 0; j < dg; ++j) {
        int e = selist[o0 + j];
        int dst = ei[NE + e];
        const float4* hp = (const float4*)(h + e * EH);
        float a = Gs[5120 + t];            // b2 (xb) term
#pragma unroll
        for (int qq = 0; qq < 8; ++qq) {
            float4 hv = hp[qq];
            a += hv.x * Gs[(qq * 4 + 0) * HID + t];
            a += hv.y * Gs[(qq * 4 + 1) * HID + t];
            a += hv.z * Gs[(qq * 4 + 2) * HID + t];
            a += hv.w * Gs[(qq * 4 + 3) * HID + t];
        }
        atomicAdd(&sumb[dst * HID + t], a);
    }
}

// ---- epilogue: mean + root + bias (+relu+cvt); re-zeros sumb for next layer ----
__global__ void k_final(float* __restrict__ sumb, const float* __restrict__ G,
                        const float* __restrict__ dinv, const float* __restrict__ bias,
                        float* __restrict__ outf, ushort* __restrict__ oh,
                        ushort* __restrict__ ol, int relu_cvt) {
    int idx = blockIdx.x * 256 + threadIdx.x;
    if (idx >= NN * HID) return;
    int d = idx / HID, o = idx - d * HID;
    float sv = sumb[idx];
    sumb[idx] = 0.f;                       // ready for next layer's atomics
    float v = sv * dinv[d] + G[(size_t)d * NCOL + 5280 + o] + bias[o];
    if (relu_cvt) {
        v = fmaxf(v, 0.f);
        ushort hi, lo; split_bf16(v, hi, lo);
        oh[idx] = hi;
        ol[idx] = lo;
    } else {
        outf[idx] = v;
    }
}

extern "C" void kernel_launch(void* const* d_in, const int* in_sizes, int n_in,
                              void* d_out, int out_size, void* d_ws, size_t ws_size,
                              hipStream_t stream) {
    const float* x     = (const float*)d_in[0];
    const float* ea    = (const float*)d_in[1];
    const float* w1a   = (const float*)d_in[2];
    const float* b1a   = (const float*)d_in[3];
    const float* w2a   = (const float*)d_in[4];
    const float* b2a   = (const float*)d_in[5];
    const float* roota = (const float*)d_in[6];
    const float* biasa = (const float*)d_in[7];
    const float* w1b   = (const float*)d_in[8];
    const float* b1b   = (const float*)d_in[9];
    const float* w2b   = (const float*)d_in[10];
    const float* b2b   = (const float*)d_in[11];
    const float* rootb = (const float*)d_in[12];
    const float* biasb = (const float*)d_in[13];
    const int*   ei    = (const int*)d_in[14];
    float* out = (float*)d_out;

    char* p = (char*)d_ws;
    float* G = (float*)p;          p += (size_t)NN * NCOL * 4;        // 45.1 MB
    float* sumb = (float*)p;       p += (size_t)NN * HID * 4;         // contiguous
    int* degd = (int*)p;           p += NN * 4;                       //  with these
    int* dego = (int*)p;           p += NN * 4;                       //  two (k_zi)
    ushort* BhA = (ushort*)p;      p += (size_t)NCOL * HID * 2;
    ushort* BlA = (ushort*)p;      p += (size_t)NCOL * HID * 2;
    ushort* BhB = (ushort*)p;      p += (size_t)NCOL * HID * 2;
    ushort* BlB = (ushort*)p;      p += (size_t)NCOL * HID * 2;
    float* h_a = (float*)p;        p += (size_t)NE * EH * 4;
    float* h_b = (float*)p;        p += (size_t)NE * EH * 4;
    ushort* xh = (ushort*)p;       p += (size_t)NN * HID * 2;
    ushort* xl = (ushort*)p;       p += (size_t)NN * HID * 2;
    int* soff = (int*)p;           p += NN * 4;
    int* cursor = (int*)p;         p += NN * 4;
    float* dinv = (float*)p;       p += NN * 4;
    int* selist = (int*)p;         p += NE * 4;

    // prep (7 launches)
    k_cvt<<<(NN * HID) / 256, 256, 0, stream>>>(x, xh, xl);
    k_prepB2<<<dim3((NCOL * HID) / 256, 2), 256, 0, stream>>>(
        w2a, b2a, roota, w2b, b2b, rootb, BhA, BlA, BhB, BlB);
    k_h2<<<dim3((NE * EH) / 256, 2), 256, 0, stream>>>(ea, w1a, b1a, w1b, b1b, h_a, h_b);
    k_zi<<<(NN * HID + 2 * NN) / 256, 256, 0, stream>>>((int*)sumb, NN * HID + 2 * NN);
    k_count<<<NE / 256, 256, 0, stream>>>(ei, degd, dego);
    k_scan<<<1, 256, 0, stream>>>(dego, degd, soff, cursor, dinv);
    k_fill<<<NE / 256, 256, 0, stream>>>(ei, cursor, selist);

    struct Layer { const ushort *bh, *bl; const float *h, *bias; int relu; };
    Layer L[3] = {
        {BhA, BlA, h_a, biasa, 1},
        {BhB, BlB, h_b, biasb, 1},
        {BhB, BlB, h_b, biasb, 0},
    };
    for (int l = 0; l < 3; ++l) {
        k_gemm<<<dim3(NCOL / 128, NN / 128), 256, 0, stream>>>(xh, xl, L[l].bh, L[l].bl, G);
        k_aggr<<<NN, HID, 0, stream>>>(G, L[l].h, ei, soff, dego, selist, sumb);
        k_final<<<(NN * HID) / 256, 256, 0, stream>>>(sumb, G, dinv, L[l].bias, out,
                                                      xh, xl, L[l].relu);
    }
}